// Round 1
// baseline (1240.376 us; speedup 1.0000x reference)
//
#include <hip/hip_runtime.h>

// LSTMFeatureExtractor: 2-layer LSTM (H=128) over B=512, T=512, + a*relu(a) head.
// f16-MFMA recurrent kernels, fp32 state/accum. Weights live as MFMA A-fragments
// in VGPRs (one layer = 128 VGPR/thread f16); gates computed as gates^T so that
// i/f/g/o for a (unit,batch) pair land in the SAME lane (4 M-tiles per wave)
// -> nonlinearity is lane-local, only h does an LDS round-trip per step.

typedef _Float16 half8  __attribute__((ext_vector_type(8)));
typedef _Float16 half4_ __attribute__((ext_vector_type(4)));
typedef float    f32x4  __attribute__((ext_vector_type(4)));

#define H_    128
#define T_    512
#define B_    512
#define BCH   16              // batch per block
#define NBLK  (B_ / BCH)      // 32 blocks
#define TCH   8               // timesteps staged per LDS chunk
#define KPAD  136             // padded row: 272B = 17*16B (16B-aligned, bank-spread)

#define LOG2E 1.44269504089f

__device__ __forceinline__ float sigm_(float x) {
    // 1/(1+2^(-x*log2e))
    return __builtin_amdgcn_rcpf(1.f + __builtin_amdgcn_exp2f(-LOG2E * x));
}
__device__ __forceinline__ float tanh_(float x) {
    // 1 - 2/(2^(2x*log2e)+1)
    return 1.f - 2.f * __builtin_amdgcn_rcpf(1.f + __builtin_amdgcn_exp2f((2.f * LOG2E) * x));
}

#define MFMA16(A, Bv, C) __builtin_amdgcn_mfma_f32_16x16x32_f16((A), (Bv), (C), 0, 0, 0)

// PHASE 0: x from y (fp32, layout y[b][k][t]); writes h to ws (f16 [b][t][u]).
// PHASE 1: x from ws f16; fuses Wa head + sum_t a*relu(a); writes out fp32.
template <int PHASE>
__global__ void __launch_bounds__(512)
lstm_phase(const float* __restrict__ xsrc_f32,
           const _Float16* __restrict__ xsrc_f16,
           const float* __restrict__ Wih, const float* __restrict__ Whh,
           const float* __restrict__ bih, const float* __restrict__ bhh,
           const float* __restrict__ Wa,  const float* __restrict__ ba,
           _Float16* __restrict__ hout,
           float* __restrict__ out)
{
    __shared__ _Float16 xbuf[TCH][16][KPAD];  // x chunk, frag-readable
    __shared__ _Float16 hbuf[2][16][KPAD];    // double-buffered h

    const int tid = threadIdx.x;
    const int w   = tid >> 6;        // wave 0..7 -> owns units [16w,16w+16)
    const int l   = tid & 63;
    const int g   = l >> 4;          // k-group / row-group 0..3
    const int cl  = l & 15;          // batch column 0..15
    const int b0  = blockIdx.x * BCH;

    // ---- zero LDS (initial h state; xbuf hygiene) ----
    {
        int* p = (int*)&xbuf[0][0][0];
        for (int i = tid; i < (int)(sizeof(xbuf) / 4); i += 512) p[i] = 0;
        int* q = (int*)&hbuf[0][0][0];
        for (int i = tid; i < (int)(sizeof(hbuf) / 4); i += 512) q[i] = 0;
    }

    // ---- weight fragments (A operand, constant across steps) ----
    // A-frag for 16x16x32: lane holds A[m = l&15][k = 32*kt + 8*(l>>4) + e]
    half8 wihf[4][4], whhf[4][4];
    #pragma unroll
    for (int gt = 0; gt < 4; ++gt) {
        const int grow = gt * 128 + w * 16 + cl;   // gate row (i,f,g,o blocks)
        #pragma unroll
        for (int kt = 0; kt < 4; ++kt) {
            const float* pa = Wih + grow * H_ + kt * 32 + g * 8;
            const float* pb = Whh + grow * H_ + kt * 32 + g * 8;
            f32x4 a0 = *(const f32x4*)(pa);
            f32x4 a1 = *(const f32x4*)(pa + 4);
            f32x4 b0v = *(const f32x4*)(pb);
            f32x4 b1v = *(const f32x4*)(pb + 4);
            half8 fa, fb;
            #pragma unroll
            for (int e = 0; e < 4; ++e) {
                fa[e] = (_Float16)a0[e]; fa[e + 4] = (_Float16)a1[e];
                fb[e] = (_Float16)b0v[e]; fb[e + 4] = (_Float16)b1v[e];
            }
            wihf[gt][kt] = fa; whhf[gt][kt] = fb;
        }
    }

    // combined bias in C-frag layout: row u = w*16 + g*4 + r, col = cl
    f32x4 bias[4];
    #pragma unroll
    for (int gt = 0; gt < 4; ++gt)
        #pragma unroll
        for (int r = 0; r < 4; ++r) {
            const int R = gt * 128 + w * 16 + g * 4 + r;
            bias[gt][r] = bih[R] + bhh[R];
        }

    // head fragments (phase 1): wave w owns output rows j in [16w,16w+16)
    half8 waf[4];
    f32x4 ba4  = {0.f, 0.f, 0.f, 0.f};
    f32x4 oacc = {0.f, 0.f, 0.f, 0.f};
    if constexpr (PHASE == 1) {
        #pragma unroll
        for (int kt = 0; kt < 4; ++kt) {
            const float* p = Wa + (w * 16 + cl) * H_ + kt * 32 + g * 8;
            f32x4 a0 = *(const f32x4*)(p);
            f32x4 a1 = *(const f32x4*)(p + 4);
            half8 f;
            #pragma unroll
            for (int e = 0; e < 4; ++e) { f[e] = (_Float16)a0[e]; f[e + 4] = (_Float16)a1[e]; }
            waf[kt] = f;
        }
        #pragma unroll
        for (int r = 0; r < 4; ++r) ba4[r] = ba[w * 16 + g * 4 + r];
    }

    float cst[4] = {0.f, 0.f, 0.f, 0.f};   // cell state (fp32, lane-resident)
    __syncthreads();

    for (int t = 0; t < T_; ++t) {
        const int tb = t & (TCH - 1);
        if (tb == 0) {
            // ---- stage next TCH timesteps into xbuf ----
            if constexpr (PHASE == 0) {
                // x[b][t][k] = y[b][k][t]; 16b*128k rows, 8 t's each
                #pragma unroll
                for (int rr = 0; rr < 4; ++rr) {
                    const int q = tid + rr * 512;       // 0..2047
                    const int b = q >> 7, k = q & 127;
                    const float* src = xsrc_f32 + ((size_t)((b0 + b) * H_ + k)) * T_ + t;
                    f32x4 v0 = *(const f32x4*)(src);
                    f32x4 v1 = *(const f32x4*)(src + 4);
                    #pragma unroll
                    for (int e = 0; e < 4; ++e) {
                        xbuf[e][b][k]     = (_Float16)v0[e];
                        xbuf[e + 4][b][k] = (_Float16)v1[e];
                    }
                }
            } else {
                // ws h0[b][t][u] f16 contiguous
                const int pq = tid >> 2;                 // 0..127
                const int b = pq >> 3, trow = pq & 7;
                const int u0 = (tid & 3) * 32;
                const _Float16* src =
                    xsrc_f16 + ((size_t)(b0 + b) * T_ + (t + trow)) * H_ + u0;
                #pragma unroll
                for (int e = 0; e < 4; ++e) {
                    half8 v = *(const half8*)(src + e * 8);
                    *(half8*)&xbuf[trow][b][u0 + e * 8] = v;
                }
            }
            __syncthreads();
        }

        const int rd = (t ^ 1) & 1;   // read h_{t-1}
        const int wr = t & 1;         // write h_t

        f32x4 acc0 = bias[0], acc1 = bias[1], acc2 = bias[2], acc3 = bias[3];
        half8 hf[4];
        #pragma unroll
        for (int kt = 0; kt < 4; ++kt) {
            const int ko = kt * 32 + g * 8;
            const half8 xf = *(const half8*)&xbuf[tb][cl][ko];
            hf[kt]         = *(const half8*)&hbuf[rd][cl][ko];
            acc0 = MFMA16(wihf[0][kt], xf, acc0);
            acc1 = MFMA16(wihf[1][kt], xf, acc1);
            acc2 = MFMA16(wihf[2][kt], xf, acc2);
            acc3 = MFMA16(wihf[3][kt], xf, acc3);
            acc0 = MFMA16(whhf[0][kt], hf[kt], acc0);
            acc1 = MFMA16(whhf[1][kt], hf[kt], acc1);
            acc2 = MFMA16(whhf[2][kt], hf[kt], acc2);
            acc3 = MFMA16(whhf[3][kt], hf[kt], acc3);
        }

        if constexpr (PHASE == 1) {
            if (t > 0) {  // head term for h1(t-1); t=0 has no previous h
                f32x4 aacc = ba4;
                #pragma unroll
                for (int kt = 0; kt < 4; ++kt) aacc = MFMA16(waf[kt], hf[kt], aacc);
                #pragma unroll
                for (int r = 0; r < 4; ++r) {
                    const float a = aacc[r];
                    oacc[r] += a * fmaxf(a, 0.f);
                }
            }
        }

        // ---- lane-local nonlinearity: this lane holds i,f,g,o for
        //      units u = w*16 + g*4 + r (r=0..3), batch b0+cl ----
        half4_ h4;
        #pragma unroll
        for (int r = 0; r < 4; ++r) {
            const float i_ = acc0[r], f_ = acc1[r], g_ = acc2[r], o_ = acc3[r];
            const float is = sigm_(i_);
            const float fs = sigm_(f_);
            const float gt_ = tanh_(g_);
            const float os = sigm_(o_);
            cst[r] = fs * cst[r] + is * gt_;
            h4[r] = (_Float16)(os * tanh_(cst[r]));
        }
        const int u0 = w * 16 + g * 4;
        *(half4_*)&hbuf[wr][cl][u0] = h4;
        if constexpr (PHASE == 0) {
            *(half4_*)&hout[((size_t)(b0 + cl) * T_ + t) * H_ + u0] = h4;
        }
        __syncthreads();
    }

    if constexpr (PHASE == 1) {
        // final head term for h1(T-1), sitting in hbuf[(T_-1)&1 == 1]
        f32x4 aacc = ba4;
        #pragma unroll
        for (int kt = 0; kt < 4; ++kt) {
            const half8 hfv = *(const half8*)&hbuf[1][cl][kt * 32 + g * 8];
            aacc = MFMA16(waf[kt], hfv, aacc);
        }
        #pragma unroll
        for (int r = 0; r < 4; ++r) {
            const float a = aacc[r];
            oacc[r] += a * fmaxf(a, 0.f);
        }
        *(f32x4*)&out[(size_t)(b0 + cl) * H_ + w * 16 + g * 4] = oacc;
    }
}

extern "C" void kernel_launch(void* const* d_in, const int* in_sizes, int n_in,
                              void* d_out, int out_size, void* d_ws, size_t ws_size,
                              hipStream_t stream) {
    const float* y    = (const float*)d_in[0];
    const float* Wih0 = (const float*)d_in[1];
    const float* Whh0 = (const float*)d_in[2];
    const float* bih0 = (const float*)d_in[3];
    const float* bhh0 = (const float*)d_in[4];
    const float* Wih1 = (const float*)d_in[5];
    const float* Whh1 = (const float*)d_in[6];
    const float* bih1 = (const float*)d_in[7];
    const float* bhh1 = (const float*)d_in[8];
    const float* Wa   = (const float*)d_in[9];
    const float* ba   = (const float*)d_in[10];
    float* out = (float*)d_out;

    // ws: layer-0 hidden states, f16 [B][T][H] = 64 MiB
    _Float16* h0ws = (_Float16*)d_ws;

    lstm_phase<0><<<NBLK, 512, 0, stream>>>(y, nullptr, Wih0, Whh0, bih0, bhh0,
                                            nullptr, nullptr, h0ws, nullptr);
    lstm_phase<1><<<NBLK, 512, 0, stream>>>(nullptr, h0ws, Wih1, Whh1, bih1, bhh1,
                                            Wa, ba, nullptr, out);
}

// Round 2
// 860.284 us; speedup vs baseline: 1.4418x; 1.4418x over previous
//
#include <hip/hip_runtime.h>

// LSTMFeatureExtractor: 2-layer LSTM (H=128) over B=512, T=512, + a*relu(a) head.
// Round 2: producer/consumer pipeline — 64 blocks run layer0 (blocks 0-31) and
// layer1+head (blocks 32-63) CONCURRENTLY, chunk-synchronized (8 steps) through
// ws with agent-scope release/acquire flags. MFMA accumulator chains split
// (ih/hh separate) to halve dependency depth.

typedef _Float16 half8  __attribute__((ext_vector_type(8)));
typedef _Float16 half4_ __attribute__((ext_vector_type(4)));
typedef float    f32x4  __attribute__((ext_vector_type(4)));

#define H_    128
#define T_    512
#define B_    512
#define BCH   16              // batch per block
#define NBG   (B_ / BCH)      // 32 batch groups
#define TCH   8               // timesteps per chunk (pipeline granularity)
#define KPAD  136             // padded LDS row: 272B

#define LOG2E 1.44269504089f

__device__ __forceinline__ float sigm_(float x) {
    return __builtin_amdgcn_rcpf(1.f + __builtin_amdgcn_exp2f(-LOG2E * x));
}
__device__ __forceinline__ float tanh_(float x) {
    return 1.f - 2.f * __builtin_amdgcn_rcpf(1.f + __builtin_amdgcn_exp2f((2.f * LOG2E) * x));
}

#define MFMA16(A, Bv, C) __builtin_amdgcn_mfma_f32_16x16x32_f16((A), (Bv), (C), 0, 0, 0)

// role 0: layer0, x from y (fp32 [b][k][t]), h -> h0ws (f16 [b][t][u]), flag release.
// role 1: layer1, x from h0ws (flag acquire), fused Wa head + sum a*relu(a) -> out.
__global__ void __launch_bounds__(512)
lstm_fused(const float* __restrict__ y,
           const float* __restrict__ Wih0, const float* __restrict__ Whh0,
           const float* __restrict__ bih0, const float* __restrict__ bhh0,
           const float* __restrict__ Wih1, const float* __restrict__ Whh1,
           const float* __restrict__ bih1, const float* __restrict__ bhh1,
           const float* __restrict__ Wa,  const float* __restrict__ ba,
           _Float16* __restrict__ h0ws,
           int* __restrict__ flags,      // nullptr => no pipeline sync
           float* __restrict__ out,
           int roleBase, int doPipe)
{
    __shared__ _Float16 xbuf[TCH][16][KPAD];
    __shared__ _Float16 hbuf[2][16][KPAD];

    const int tid  = threadIdx.x;
    const int w    = tid >> 6;
    const int l    = tid & 63;
    const int g    = l >> 4;
    const int cl   = l & 15;
    const int role = (blockIdx.x >> 5) + roleBase;   // block-uniform
    const int bg   = blockIdx.x & 31;
    const int b0   = bg * BCH;

    // ---- zero LDS ----
    {
        int* p = (int*)&xbuf[0][0][0];
        for (int i = tid; i < (int)(sizeof(xbuf) / 4); i += 512) p[i] = 0;
        int* q = (int*)&hbuf[0][0][0];
        for (int i = tid; i < (int)(sizeof(hbuf) / 4); i += 512) q[i] = 0;
    }

    const float* Wih = role ? Wih1 : Wih0;
    const float* Whh = role ? Whh1 : Whh0;
    const float* bihp = role ? bih1 : bih0;
    const float* bhhp = role ? bhh1 : bhh0;

    // ---- weight A-fragments (lane holds A[m=l&15][k=32kt+8g+e]) ----
    half8 wihf[4][4], whhf[4][4];
    #pragma unroll
    for (int gt = 0; gt < 4; ++gt) {
        const int grow = gt * 128 + w * 16 + cl;
        #pragma unroll
        for (int kt = 0; kt < 4; ++kt) {
            const float* pa = Wih + grow * H_ + kt * 32 + g * 8;
            const float* pb = Whh + grow * H_ + kt * 32 + g * 8;
            f32x4 a0 = *(const f32x4*)(pa);
            f32x4 a1 = *(const f32x4*)(pa + 4);
            f32x4 c0 = *(const f32x4*)(pb);
            f32x4 c1 = *(const f32x4*)(pb + 4);
            half8 fa, fb;
            #pragma unroll
            for (int e = 0; e < 4; ++e) {
                fa[e] = (_Float16)a0[e]; fa[e + 4] = (_Float16)a1[e];
                fb[e] = (_Float16)c0[e]; fb[e + 4] = (_Float16)c1[e];
            }
            wihf[gt][kt] = fa; whhf[gt][kt] = fb;
        }
    }

    f32x4 bias[4];
    #pragma unroll
    for (int gt = 0; gt < 4; ++gt)
        #pragma unroll
        for (int r = 0; r < 4; ++r) {
            const int R = gt * 128 + w * 16 + g * 4 + r;
            bias[gt][r] = bihp[R] + bhhp[R];
        }

    half8 waf[4];
    f32x4 ba4  = {0.f, 0.f, 0.f, 0.f};
    f32x4 oacc = {0.f, 0.f, 0.f, 0.f};
    if (role == 1) {
        #pragma unroll
        for (int kt = 0; kt < 4; ++kt) {
            const float* p = Wa + (w * 16 + cl) * H_ + kt * 32 + g * 8;
            f32x4 a0 = *(const f32x4*)(p);
            f32x4 a1 = *(const f32x4*)(p + 4);
            half8 f;
            #pragma unroll
            for (int e = 0; e < 4; ++e) { f[e] = (_Float16)a0[e]; f[e + 4] = (_Float16)a1[e]; }
            waf[kt] = f;
        }
        #pragma unroll
        for (int r = 0; r < 4; ++r) ba4[r] = ba[w * 16 + g * 4 + r];
    }

    float cst[4] = {0.f, 0.f, 0.f, 0.f};
    __syncthreads();

    for (int t = 0; t < T_; ++t) {
        const int tb = t & (TCH - 1);
        if (tb == 0) {
            const int c = t >> 3;
            if (role == 0) {
                // stage y[b][k][t..t+7] -> xbuf (f16)
                #pragma unroll
                for (int rr = 0; rr < 4; ++rr) {
                    const int q = tid + rr * 512;
                    const int b = q >> 7, k = q & 127;
                    const float* src = y + ((size_t)((b0 + b) * H_ + k)) * T_ + t;
                    f32x4 v0 = *(const f32x4*)(src);
                    f32x4 v1 = *(const f32x4*)(src + 4);
                    #pragma unroll
                    for (int e = 0; e < 4; ++e) {
                        xbuf[e][b][k]     = (_Float16)v0[e];
                        xbuf[e + 4][b][k] = (_Float16)v1[e];
                    }
                }
            } else {
                if (doPipe) {
                    if (tid == 0) {
                        while (__hip_atomic_load(&flags[bg], __ATOMIC_ACQUIRE,
                                                 __HIP_MEMORY_SCOPE_AGENT) < c + 1)
                            __builtin_amdgcn_s_sleep(2);
                    }
                    __syncthreads();
                }
                const int pq = tid >> 2;
                const int b = pq >> 3, trow = pq & 7;
                const int u0 = (tid & 3) * 32;
                const _Float16* src =
                    h0ws + ((size_t)(b0 + b) * T_ + (t + trow)) * H_ + u0;
                #pragma unroll
                for (int e = 0; e < 4; ++e) {
                    half8 v = *(const half8*)(src + e * 8);
                    *(half8*)&xbuf[trow][b][u0 + e * 8] = v;
                }
            }
            __syncthreads();
        }

        const int rd = (t ^ 1) & 1;
        const int wr = t & 1;

        // split accumulator chains: ih (seeded with bias) and hh (zero)
        f32x4 ai0 = bias[0], ai1 = bias[1], ai2 = bias[2], ai3 = bias[3];
        f32x4 ah0 = {0,0,0,0}, ah1 = {0,0,0,0}, ah2 = {0,0,0,0}, ah3 = {0,0,0,0};
        half8 hf[4];
        #pragma unroll
        for (int kt = 0; kt < 4; ++kt) {
            const int ko = kt * 32 + g * 8;
            const half8 xf = *(const half8*)&xbuf[tb][cl][ko];
            hf[kt]         = *(const half8*)&hbuf[rd][cl][ko];
            ai0 = MFMA16(wihf[0][kt], xf, ai0);
            ai1 = MFMA16(wihf[1][kt], xf, ai1);
            ai2 = MFMA16(wihf[2][kt], xf, ai2);
            ai3 = MFMA16(wihf[3][kt], xf, ai3);
            ah0 = MFMA16(whhf[0][kt], hf[kt], ah0);
            ah1 = MFMA16(whhf[1][kt], hf[kt], ah1);
            ah2 = MFMA16(whhf[2][kt], hf[kt], ah2);
            ah3 = MFMA16(whhf[3][kt], hf[kt], ah3);
        }

        if (role == 1 && t > 0) {    // head term for h1(t-1)
            f32x4 aacc = ba4;
            #pragma unroll
            for (int kt = 0; kt < 4; ++kt) aacc = MFMA16(waf[kt], hf[kt], aacc);
            #pragma unroll
            for (int r = 0; r < 4; ++r) {
                const float a = aacc[r];
                oacc[r] += a * fmaxf(a, 0.f);
            }
        }

        half4_ h4;
        #pragma unroll
        for (int r = 0; r < 4; ++r) {
            const float i_ = ai0[r] + ah0[r];
            const float f_ = ai1[r] + ah1[r];
            const float g_ = ai2[r] + ah2[r];
            const float o_ = ai3[r] + ah3[r];
            const float is = sigm_(i_);
            const float fs = sigm_(f_);
            const float gt_ = tanh_(g_);
            const float os = sigm_(o_);
            cst[r] = fs * cst[r] + is * gt_;
            h4[r] = (_Float16)(os * tanh_(cst[r]));
        }
        const int u0 = w * 16 + g * 4;
        *(half4_*)&hbuf[wr][cl][u0] = h4;
        if (role == 0) {
            *(half4_*)&h0ws[((size_t)(b0 + cl) * T_ + t) * H_ + u0] = h4;
        }
        __syncthreads();

        if (role == 0 && tb == TCH - 1 && doPipe) {
            if (tid == 0)
                __hip_atomic_store(&flags[bg], (t >> 3) + 1, __ATOMIC_RELEASE,
                                   __HIP_MEMORY_SCOPE_AGENT);
        }
    }

    if (role == 1) {
        // final head term for h1(T-1) in hbuf[1]
        f32x4 aacc = ba4;
        #pragma unroll
        for (int kt = 0; kt < 4; ++kt) {
            const half8 hfv = *(const half8*)&hbuf[1][cl][kt * 32 + g * 8];
            aacc = MFMA16(waf[kt], hfv, aacc);
        }
        #pragma unroll
        for (int r = 0; r < 4; ++r) {
            const float a = aacc[r];
            oacc[r] += a * fmaxf(a, 0.f);
        }
        *(f32x4*)&out[(size_t)(b0 + cl) * H_ + w * 16 + g * 4] = oacc;
    }
}

extern "C" void kernel_launch(void* const* d_in, const int* in_sizes, int n_in,
                              void* d_out, int out_size, void* d_ws, size_t ws_size,
                              hipStream_t stream) {
    const float* y    = (const float*)d_in[0];
    const float* Wih0 = (const float*)d_in[1];
    const float* Whh0 = (const float*)d_in[2];
    const float* bih0 = (const float*)d_in[3];
    const float* bhh0 = (const float*)d_in[4];
    const float* Wih1 = (const float*)d_in[5];
    const float* Whh1 = (const float*)d_in[6];
    const float* bih1 = (const float*)d_in[7];
    const float* bhh1 = (const float*)d_in[8];
    const float* Wa   = (const float*)d_in[9];
    const float* ba   = (const float*)d_in[10];
    float* out = (float*)d_out;

    const size_t H0_BYTES = (size_t)B_ * T_ * H_ * sizeof(_Float16); // 64 MiB
    _Float16* h0ws = (_Float16*)d_ws;

    if (ws_size >= H0_BYTES + 256) {
        int* flags = (int*)((char*)d_ws + H0_BYTES);
        hipMemsetAsync(flags, 0, 256, stream);
        lstm_fused<<<2 * NBG, 512, 0, stream>>>(y, Wih0, Whh0, bih0, bhh0,
                                                Wih1, Whh1, bih1, bhh1, Wa, ba,
                                                h0ws, flags, out, 0, 1);
    } else {
        // fallback: sequential two-pass (no pipeline flags)
        lstm_fused<<<NBG, 512, 0, stream>>>(y, Wih0, Whh0, bih0, bhh0,
                                            Wih1, Whh1, bih1, bhh1, Wa, ba,
                                            h0ws, nullptr, out, 0, 0);
        lstm_fused<<<NBG, 512, 0, stream>>>(y, Wih0, Whh0, bih0, bhh0,
                                            Wih1, Whh1, bih1, bhh1, Wa, ba,
                                            h0ws, nullptr, out, 1, 0);
    }
}